// Round 12
// baseline (114.531 us; speedup 1.0000x reference)
//
#include <hip/hip_runtime.h>

#define NXC 65536
#define TT 32
#define HH 128
#define TABN 6145                // lerp base entries over [-1, 2], delta = 2^-11
#define TABNP 6146               // stored values (one extra for last slope)
#define TABLO (-1.0f)
#define TABINV 2048.0f
#define OUTW 32                  // output cells per window
#define VC 3                     // window cells per lane
#define WINW 192                 // VC * 64
#define HALO 80                  // (WINW - OUTW) / 2; >= 64 stages per chunk
#define NW 2                     // independent windows per wave (ILP-2)

typedef __attribute__((ext_vector_type(8))) short bf16x8;
typedef __attribute__((ext_vector_type(4))) float f32x4;
typedef unsigned short u16;

__device__ __forceinline__ float bf2f(u16 b) {
    union { unsigned int u; float f; } v; v.u = ((unsigned int)b) << 16; return v.f;
}
__device__ __forceinline__ u16 f2bf(float f) {
    union { float f; unsigned int u; } v; v.f = f;
    return (u16)((v.u + 0x7fffu + ((v.u >> 16) & 1u)) >> 16);  // RNE
}
__device__ __forceinline__ bool is_bf16_mode(const void* t) {
    return ((const u16*)t)[1] != 0;  // f32: hi half of t[0]=0.0f; bf16: t[1]=0x3C24
}

#if __has_builtin(__builtin_amdgcn_exp2f)
#define EXP2F(x) __builtin_amdgcn_exp2f(x)
#else
#define EXP2F(x) exp2f(x)
#endif
#if __has_builtin(__builtin_amdgcn_rcpf)
#define RCPF(x) __builtin_amdgcn_rcpf(x)
#else
#define RCPF(x) (1.0f / (x))
#endif
// fract(f) == f - (float)(int)f exactly for clamped f in [0, TABN-1]
#if __has_builtin(__builtin_amdgcn_fractf)
#define FRACTF(x) __builtin_amdgcn_fractf(x)
#else
#define FRACTF(x) ((x) - floorf(x))
#endif

__device__ __forceinline__ float fast_tanh(float x) {
    float e = EXP2F(x * 2.8853900817779268f);
    return 1.0f - 2.0f * RCPF(e + 1.0f);
}

// Whole-wave lane shifts via DPP (VALU, off the LDS pipe). HW-verified
// bit-identical to __shfl_up/__shfl_down(x,1) incl. edge lanes (R8/R9).
__device__ __forceinline__ float dpp_up1(float x) {
    int xi = __float_as_int(x);
    int r = __builtin_amdgcn_update_dpp(xi, xi, 0x138, 0xf, 0xf, false);
    return __int_as_float(r);
}
__device__ __forceinline__ float dpp_dn1(float x) {
    int xi = __float_as_int(x);
    int r = __builtin_amdgcn_update_dpp(xi, xi, 0x130, 0xf, 0xf, false);
    return __int_as_float(r);
}

// W2[k][n] -> MFMA B-fragment order (bf16). Verified round-0 kernel.
__global__ void w2swz_kernel(const void* t, const void* W2,
                             u16* __restrict__ w2frag) {
    bool bf = is_bf16_mode(t);
    int i = blockIdx.x * 256 + threadIdx.x;  // [0, 16384)
    int j = i & 7;
    int lane = (i >> 3) & 63;
    int ks = (i >> 9) & 3;
    int nt = i >> 11;
    int k = ks * 32 + (lane >> 4) * 8 + j;
    int n = nt * 16 + (lane & 15);
    w2frag[i] = bf ? ((const u16*)W2)[k * HH + n]
                   : f2bf(((const float*)W2)[k * HH + n]);
}

// Tabulate a(u) on grid u_e = TABLO + e/TABINV via the MFMA MLP.
// Verified round-0 kernel (fragments read from global w2frag, coalesced).
__global__ __launch_bounds__(256) void tabbuild_kernel(
    const void* traw, const void* W1, const void* W3,
    const u16* __restrict__ w2frag, float* __restrict__ atab) {
    __shared__ float w1s[HH];
    __shared__ float w3s[HH];
    bool bf = is_bf16_mode(traw);
    int tid = threadIdx.x;
    if (tid < HH)
        w1s[tid] = bf ? bf2f(((const u16*)W1)[tid]) : ((const float*)W1)[tid];
    else
        w3s[tid - HH] = bf ? bf2f(((const u16*)W3)[tid - HH])
                           : ((const float*)W3)[tid - HH];
    __syncthreads();

    int lane = tid & 63;
    int wave = tid >> 6;
    int q = lane >> 4;
    int m = lane & 15;
    int base = (blockIdx.x * 4 + wave) * 16;
    float uin = TABLO + (float)(base + m) * (1.0f / TABINV);

    bf16x8 afrag[4];
#pragma unroll
    for (int ks = 0; ks < 4; ++ks)
#pragma unroll
        for (int j = 0; j < 8; ++j) {
            float h = fast_tanh(uin * w1s[ks * 32 + q * 8 + j]);
            afrag[ks][j] = (short)f2bf(h);
        }

    const bf16x8* w2f = (const bf16x8*)w2frag;   // global, coalesced 1KB/wave
    float p0 = 0.f, p1 = 0.f, p2 = 0.f, p3 = 0.f;
#pragma unroll
    for (int nt = 0; nt < 8; ++nt) {
        f32x4 acc = {0.f, 0.f, 0.f, 0.f};
#pragma unroll
        for (int ks = 0; ks < 4; ++ks) {
            bf16x8 b = w2f[(nt * 4 + ks) * 64 + lane];
            acc = __builtin_amdgcn_mfma_f32_16x16x32_bf16(afrag[ks], b, acc, 0, 0, 0);
        }
        float w3v = w3s[nt * 16 + m];
        p0 += fast_tanh(acc[0]) * w3v;
        p1 += fast_tanh(acc[1]) * w3v;
        p2 += fast_tanh(acc[2]) * w3v;
        p3 += fast_tanh(acc[3]) * w3v;
    }
#pragma unroll
    for (int sh = 1; sh < 16; sh <<= 1) {
        p0 += __shfl_xor(p0, sh, 64);
        p1 += __shfl_xor(p1, sh, 64);
        p2 += __shfl_xor(p2, sh, 64);
        p3 += __shfl_xor(p3, sh, 64);
    }
    int r = m & 3;
    float a = (r == 0) ? p0 : (r == 1) ? p1 : (r == 2) ? p2 : p3;
    if (m < 4) {
        int e = base + q * 4 + r;
        if (e < TABNP) atab[e] = a;
    }
}

// One time-chunk (<=16 RK4 steps). R11 session-best per-cell math with
// ILP-2: each wave runs TWO independent 192-cell windows (VC=3, halo
// 80/80, owned 32 cells each, adjacent output regions). The two windows'
// per-stage chains (index calc -> divergent ds_read_b64 gather -> flux ->
// update) are fully independent, so one window's ~120-200cy gather
// latency hides under the other's issue — the in-wave analog of the
// cross-stage pipelining R10 could not achieve (only ~30-60cy of overlap
// work existed in a single window). Wave/block count unchanged: 1024
// waves, 256 blocks, 1 block/CU, barrier-free. All per-cell expression
// trees byte-identical to R11 (unconditional update + edge-block ghost
// repair, float2 (value,slope) table, pipelined lookups, DPP shifts,
// FRACTF, clamped index, frozen ghost BCs). s0==0 converts raw u0 and
// passes it through as output row 0.
__global__ __launch_bounds__(256) void chunk_kernel(
    const void* traw, const void* uin, float* __restrict__ uout,
    const void* Draw, const void* BCraw, const float* __restrict__ atab,
    void* __restrict__ outbase, int s0, int nsteps) {
    __shared__ __align__(16) float2 tab[TABN];
    __shared__ float t32s[TT];

    int tid = threadIdx.x;
    bool bf = is_bf16_mode(traw);

    // (value, slope) table: float4 loads, float4 LDS stores (R4-verified)
    for (int e = tid * 4; e < TABN - 1; e += 1024) {
        float4 qv = *(const float4*)(atab + e);
        float nx = atab[e + 4];
        float4 lo = make_float4(qv.x, qv.y - qv.x, qv.y, qv.z - qv.y);
        float4 hi = make_float4(qv.z, qv.w - qv.z, qv.w, nx - qv.w);
        *(float4*)(&tab[e]) = lo;
        *(float4*)(&tab[e + 2]) = hi;
    }
    if (tid == 0)
        tab[TABN - 1] = make_float2(atab[TABN - 1], atab[TABN] - atab[TABN - 1]);
    if (tid < TT)
        t32s[tid] = bf ? bf2f(((const u16*)traw)[tid]) : ((const float*)traw)[tid];

    float d   = bf ? bf2f(((const u16*)Draw)[0])  : ((const float*)Draw)[0];
    float bc0 = bf ? bf2f(((const u16*)BCraw)[0]) : ((const float*)BCraw)[0];
    float bc1 = bf ? bf2f(((const u16*)BCraw)[1]) : ((const float*)BCraw)[1];

    int lane = tid & 63;
    int wid = blockIdx.x * 4 + (tid >> 6);     // wave id [0, 1024)
    int i0 = lane * VC;                         // window-local first cell
    bool first = (s0 == 0);
    // only the first and last blocks contain out-of-domain (ghost) lanes
    bool edgeblk = (blockIdx.x == 0) || (blockIdx.x == gridDim.x - 1);

    int gbw[NW];
    float v[NW][VC], ub[NW][VC], gfix[NW][VC];
    bool gok[NW][VC], own[VC];
#pragma unroll
    for (int j = 0; j < VC; ++j) {
        int i = i0 + j;
        own[j] = (i >= HALO) && (i < HALO + OUTW);   // same for both windows
    }
#pragma unroll
    for (int w = 0; w < NW; ++w) {
        gbw[w] = (wid * NW + w) * OUTW - HALO + i0;  // lane's first cell
#pragma unroll
        for (int j = 0; j < VC; ++j) {
            int g = gbw[w] + j;
            gok[w][j] = (g >= 0) && (g < NXC);
            float x;
            if (first) {
                if (bf) {
                    u16 raw = gok[w][j] ? ((const u16*)uin)[g] : (u16)0;
                    x = bf2f(raw);
                    if (own[j]) ((u16*)outbase)[g] = raw;   // row 0 passthrough
                } else {
                    float raw = gok[w][j] ? ((const float*)uin)[g] : 0.f;
                    x = raw;
                    if (own[j]) ((float*)outbase)[g] = raw;
                }
            } else {
                x = gok[w][j] ? ((const float*)uin)[g] : 0.f;
            }
            if (!gok[w][j]) x = (g < 0) ? bc0 : bc1;  // frozen ghost BC cells
            gfix[w][j] = x;
            v[w][j] = x;
            ub[w][j] = x;
        }
    }
    __syncthreads();  // table + t32s ready; no barriers after this

    // pending table lookup per cell: frac + (value, slope), from current v
    float pf[NW][VC];
    float2 pt[NW][VC];
#pragma unroll
    for (int w = 0; w < NW; ++w)
#pragma unroll
        for (int j = 0; j < VC; ++j) {
            float f = fmaf(v[w][j], TABINV, (-TABLO) * TABINV);
            f = fminf(fmaxf(f, 0.0f), (float)(TABN - 1));
            int e0 = (int)f;
            pf[w][j] = FRACTF(f);
            pt[w][j] = tab[e0];              // ds_read_b64, in flight
        }

    for (int st = 0; st < nsteps; ++st) {
        int step = s0 + st;
        float dt = t32s[step + 1] - t32s[step];
        float dt2 = 0.5f * dt, dt6 = dt * (1.0f / 6.0f);
        float kacc[NW][VC], kv[NW][VC];
#pragma unroll
        for (int w = 0; w < NW; ++w)
#pragma unroll
            for (int j = 0; j < VC; ++j) kacc[w][j] = 0.f;
#pragma unroll
        for (int s = 0; s < 4; ++s) {
            float cnext = (s < 2) ? dt2 : dt;
            float wgt = (s == 1 || s == 2) ? 2.f : 1.f;
            float vup[NW], vdn[NW];
#pragma unroll
            for (int w = 0; w < NW; ++w) {
                vup[w] = dpp_up1(v[w][VC - 1]);   // left nbr of cell j=0
                vdn[w] = dpp_dn1(v[w][0]);        // right nbr of j=VC-1
            }
#pragma unroll
            for (int w = 0; w < NW; ++w)
#pragma unroll
                for (int j = 0; j < VC; ++j) {
                    float vc = v[w][j];
                    float vl = (j == 0) ? vup[w] : v[w][j - 1];
                    float vr = (j == VC - 1) ? vdn[w] : v[w][j + 1];
                    float a = fmaf(pf[w][j], pt[w][j].y, pt[w][j].x);
                    float ap = fmaxf(a, 0.f);
                    float am = fminf(a, 0.f);
                    kv[w][j] = (vl - vc) * (d + ap) + (vr - vc) * (d - am);
                }
#pragma unroll
            for (int w = 0; w < NW; ++w)
#pragma unroll
                for (int j = 0; j < VC; ++j) {
                    kacc[w][j] += wgt * kv[w][j];
                    float nv = (s < 3) ? fmaf(cnext, kv[w][j], ub[w][j])
                                       : fmaf(dt6, kacc[w][j], ub[w][j]);
                    v[w][j] = nv;               // unconditional (no cndmask)
                    if (s == 3) ub[w][j] = nv;
                    // issue next stage's lookup from the just-updated value
                    float f = fmaf(v[w][j], TABINV, (-TABLO) * TABINV);
                    f = fminf(fmaxf(f, 0.0f), (float)(TABN - 1));
                    int e0 = (int)f;
                    pf[w][j] = FRACTF(f);
                    pt[w][j] = tab[e0];
                }
            if (edgeblk) {   // block-uniform: skipped by 254/256 blocks
#pragma unroll
                for (int w = 0; w < NW; ++w)
#pragma unroll
                    for (int j = 0; j < VC; ++j)
                        if (!gok[w][j]) { v[w][j] = gfix[w][j]; ub[w][j] = gfix[w][j]; }
            }
        }
        if (bf) {
            u16* orow = (u16*)outbase + (size_t)(step + 1) * NXC;
#pragma unroll
            for (int w = 0; w < NW; ++w)
#pragma unroll
                for (int j = 0; j < VC; ++j)
                    if (own[j]) orow[gbw[w] + j] = f2bf(ub[w][j]);
        } else {
            float* orow = (float*)outbase + (size_t)(step + 1) * NXC;
#pragma unroll
            for (int w = 0; w < NW; ++w)
#pragma unroll
                for (int j = 0; j < VC; ++j)
                    if (own[j]) orow[gbw[w] + j] = ub[w][j];
        }
    }
    // chunk-final state for owned cells (skipped for the last chunk)
    if (uout != nullptr) {
#pragma unroll
        for (int w = 0; w < NW; ++w)
#pragma unroll
            for (int j = 0; j < VC; ++j)
                if (own[j]) uout[gbw[w] + j] = ub[w][j];
    }
}

extern "C" void kernel_launch(void* const* d_in, const int* in_sizes, int n_in,
                              void* d_out, int out_size, void* d_ws,
                              size_t ws_size, hipStream_t stream) {
    const void* t  = d_in[0];
    const void* u0 = d_in[1];
    const void* W1 = d_in[2];
    const void* W2 = d_in[3];
    const void* W3 = d_in[4];
    const void* Dp = d_in[5];
    const void* BC = d_in[6];

    float* atab = (float*)d_ws;                    // TABNP+2 floats
    u16* w2frag = (u16*)(atab + TABNP + 2);        // offset 24592 B, 16B-aligned
    float* uB = (float*)(w2frag + 16384);          // NXC f32 mid-state

    w2swz_kernel<<<64, 256, 0, stream>>>(t, W2, w2frag);
    tabbuild_kernel<<<(TABNP + 63) / 64, 256, 0, stream>>>(t, W1, W3, w2frag, atab);

    const int grid = NXC / (OUTW * NW * 4);        // 256 blocks, 1/CU
    chunk_kernel<<<grid, 256, 0, stream>>>(t, u0, uB, Dp, BC, atab, d_out, 0, 16);
    chunk_kernel<<<grid, 256, 0, stream>>>(t, uB, nullptr, Dp, BC, atab, d_out, 16, 15);
}